// Round 10
// baseline (160.109 us; speedup 1.0000x reference)
//
#include <hip/hip_runtime.h>
#include <hip/hip_bf16.h>

#define Bdim 16
#define Ndim 1024
#define Hh   4
#define HDc  128
#define L2E  1.4426950408889634f

typedef float  float4v  __attribute__((ext_vector_type(4)));
typedef int    int4v    __attribute__((ext_vector_type(4)));
typedef short  short8   __attribute__((ext_vector_type(8)));
typedef unsigned short ushort4v __attribute__((ext_vector_type(4)));
typedef unsigned int   uint2v   __attribute__((ext_vector_type(2)));
typedef _Float16 f16x2 __attribute__((ext_vector_type(2)));
typedef _Float16 half8 __attribute__((ext_vector_type(8)));

__device__ __forceinline__ unsigned short bf16_rne(float f) {
    unsigned u = __float_as_uint(f);
    u = u + 0x7FFFu + ((u >> 16) & 1u);
    return (unsigned short)(u >> 16);
}
__device__ __forceinline__ unsigned short f16u(float f) {
    union { _Float16 h; unsigned short u; } c; c.h = (_Float16)f; return c.u;
}
__device__ __forceinline__ void gl_lds16(const void* g, void* l) {
    __builtin_amdgcn_global_load_lds(
        (const __attribute__((address_space(1))) unsigned int*)g,
        (__attribute__((address_space(3))) unsigned int*)l, 16, 0, 0);
}
// p2 = max(EE*Ej2, FF*Fj2) & mask   (packed fp16, 4 VALU for 2 scores)
__device__ __forceinline__ unsigned pmax_mask(unsigned EE, unsigned FF,
                                              unsigned Ej, unsigned Fj, unsigned m) {
    union { unsigned u; f16x2 h; } a, b, c, d, r;
    a.u = EE; b.u = Ej; c.u = FF; d.u = Fj;
    r.h = __builtin_elementwise_max(a.h * b.h, c.h * d.h);
    return r.u & m;
}

// ---------- split_w: WT hi/lo [144][128] row-major + bias2[144] -------------
__global__ __launch_bounds__(256) void split_w_kernel(
    const float* __restrict__ W, const float* __restrict__ bias,
    const float* __restrict__ a,
    unsigned short* __restrict__ WTh, unsigned short* __restrict__ WTl,
    float* __restrict__ bias2)
{
    const int t = threadIdx.x, blk = blockIdx.x;
    if (blk < 16) {
        int r  = blk * 8 + (t >> 5);
        int k0 = (t & 31) * 4;
        #pragma unroll
        for (int j = 0; j < 4; ++j) {
            float f = W[(size_t)(k0 + j) * HDc + r];
            unsigned short hi = bf16_rne(f);
            WTh[r * 128 + k0 + j] = hi;
            WTl[r * 128 + k0 + j] = bf16_rne(f - __uint_as_float((unsigned)hi << 16));
        }
    } else {
        #pragma unroll
        for (int rep = 0; rep < 2; ++rep) {
            int task = t + rep * 256;
            int row = task >> 2, hh = task & 3;
            float si = 0.f, sj = 0.f;
            #pragma unroll
            for (int d4 = 0; d4 < 8; ++d4) {
                float4v wv = *(const float4v*)(W + (size_t)row * HDc + hh * 32 + d4 * 4);
                float4v av = *(const float4v*)(a + d4 * 4);
                float4v bv = *(const float4v*)(a + 32 + d4 * 4);
                #pragma unroll
                for (int kk = 0; kk < 4; ++kk) {
                    si = fmaf(wv[kk], av[kk], si);
                    sj = fmaf(wv[kk], bv[kk], sj);
                }
            }
            float vi = si * L2E, vj = sj * L2E;
            unsigned short hi = bf16_rne(vi);
            WTh[(128 + hh) * 128 + row] = hi;
            WTl[(128 + hh) * 128 + row] = bf16_rne(vi - __uint_as_float((unsigned)hi << 16));
            unsigned short hj = bf16_rne(vj);
            WTh[(132 + hh) * 128 + row] = hj;
            WTl[(132 + hh) * 128 + row] = bf16_rne(vj - __uint_as_float((unsigned)hj << 16));
        }
        #pragma unroll
        for (int rp = 0; rp < 4; ++rp) {
            int idx = t + rp * 256;
            WTh[136 * 128 + idx] = 0;
            WTl[136 * 128 + idx] = 0;
        }
        if (t < 128) {
            bias2[t] = bias[t];
        } else if (t < 136) {
            int z = t - 128;
            const float* av = (z < 4) ? a : a + 32;
            int hh = z & 3;
            float s = 0.f;
            for (int d = 0; d < 32; ++d) s = fmaf(bias[hh * 32 + d], av[d], s);
            bias2[128 + z] = s * L2E;
        } else if (t < 144) {
            bias2[t] = 0.f;
        }
    }
}

// ---------- proj: h (fp16, transposed) + per-node E/F score tables ----------
__global__ __launch_bounds__(256, 1) void proj_kernel(
    const float* __restrict__ x,
    const unsigned short* __restrict__ WTg_h, const unsigned short* __restrict__ WTg_l,
    const float* __restrict__ bias2,
    unsigned short* __restrict__ hT,
    unsigned short* __restrict__ eiE, unsigned short* __restrict__ eiF,
    unsigned short* __restrict__ ejE, unsigned short* __restrict__ ejF)
{
    __shared__ __align__(16) unsigned char smem[106496];  // xs 32K | WT 72K
    char* xls  = (char*)smem;
    char* wtls = (char*)smem + 32768;

    const int t = threadIdx.x, lane = t & 63, w = t >> 6;
    const int l16 = lane & 15, q = lane >> 4;
    const int nb = blockIdx.x * 64;
    const int b = nb >> 10, nloc = nb & 1023;

    {
        const char* gx = (const char*)(x + (size_t)nb * 128);
        int rh = lane >> 5, m = lane & 31;
        #pragma unroll
        for (int d = 0; d < 8; ++d) {
            int r = w * 16 + d * 2 + rh;
            int mg = m ^ (r & 7);
            gl_lds16(gx + (size_t)r * 512 + mg * 16, xls + (size_t)w * 8192 + d * 1024);
        }
    }
    {
        int rh = lane >> 4, m = lane & 15;
        #pragma unroll
        for (int d = 0; d < 18; ++d) {
            int n = w * 18 + d;
            if (n < 36) {
                int r = n * 4 + rh;
                gl_lds16((const char*)WTg_h + (size_t)r * 256 + (m ^ (r & 15)) * 16,
                         wtls + (size_t)n * 1024);
            } else {
                int r = (n - 36) * 4 + rh;
                gl_lds16((const char*)WTg_l + (size_t)r * 256 + (m ^ (r & 15)) * 16,
                         wtls + (size_t)n * 1024);
            }
        }
    }
    __syncthreads();

    float4v C[9];
    #pragma unroll
    for (int nt = 0; nt < 9; ++nt) C[nt] = (float4v){0.f, 0.f, 0.f, 0.f};

    #pragma unroll
    for (int ks = 0; ks < 4; ++ks) {
        short8 Ah, Al;
        {
            int r = w * 16 + l16;
            int c0 = (ks * 8 + q * 2) ^ (l16 & 7);
            int c1 = (ks * 8 + q * 2 + 1) ^ (l16 & 7);
            float4v x0 = *(const float4v*)(xls + (size_t)r * 512 + c0 * 16);
            float4v x1 = *(const float4v*)(xls + (size_t)r * 512 + c1 * 16);
            #pragma unroll
            for (int e = 0; e < 8; ++e) {
                float f = (e < 4) ? x0[e] : x1[e - 4];
                unsigned short hi = bf16_rne(f);
                Ah[e] = (short)hi;
                Al[e] = (short)bf16_rne(f - __uint_as_float((unsigned)hi << 16));
            }
        }
        #pragma unroll
        for (int nt = 0; nt < 9; ++nt) {
            const char* wb = wtls + (size_t)(nt * 16 + l16) * 256 + ((ks * 4 + q) ^ l16) * 16;
            short8 Bh = *(const short8*)wb;
            short8 Bl = *(const short8*)(wb + 36864);
            C[nt] = __builtin_amdgcn_mfma_f32_16x16x32_bf16(Ah, Bh, C[nt], 0, 0, 0);
            C[nt] = __builtin_amdgcn_mfma_f32_16x16x32_bf16(Ah, Bl, C[nt], 0, 0, 0);
            C[nt] = __builtin_amdgcn_mfma_f32_16x16x32_bf16(Al, Bh, C[nt], 0, 0, 0);
        }
    }

    {
        int node = nloc + w * 16 + q * 4;
        #pragma unroll
        for (int nt = 0; nt < 8; ++nt) {
            int col = nt * 16 + l16;
            float bv = bias2[col];
            ushort4v h4;
            #pragma unroll
            for (int r = 0; r < 4; ++r) h4[r] = f16u(C[nt][r] + bv);
            *(ushort4v*)(hT + (size_t)(b * HDc + col) * Ndim + node) = h4;
        }
        float bv = bias2[128 + l16];
        if (l16 < 8) {
            int hh = l16 & 3;
            ushort4v Ev, Fv;
            #pragma unroll
            for (int r = 0; r < 4; ++r) {
                float v = C[8][r] + bv;                 // already * log2e
                Ev[r] = f16u(__builtin_amdgcn_exp2f(v));
                Fv[r] = f16u(__builtin_amdgcn_exp2f(0.2f * v));
            }
            size_t off = (size_t)(b * Hh + hh) * Ndim + node;
            if (l16 < 4) { *(ushort4v*)(eiE + off) = Ev; *(ushort4v*)(eiF + off) = Fv; }
            else         { *(ushort4v*)(ejE + off) = Ev; *(ushort4v*)(ejF + off) = Fv; }
        }
    }
}

// ---------- gat: 32 i-rows x 4 heads, 512 threads (wave = head x i-half) ----
// grid 512 -> 2 blocks/CU, ONE dispatch round. Packed-fp16 scores, no exp.
__global__ __launch_bounds__(512, 4) void gat_kernel(
    const int* __restrict__ adj, const unsigned short* __restrict__ hT,
    const unsigned short* __restrict__ eiE, const unsigned short* __restrict__ eiF,
    const unsigned short* __restrict__ ejE, const unsigned short* __restrict__ ejF,
    float* __restrict__ out)
{
    __shared__ __align__(16) unsigned char smem[40960]; // pk 4K|ej 2K|lut|hT 32K
    unsigned int* pkl = (unsigned int*)smem;            // [32 rows][32 words]
    char* ejl = (char*)(smem + 4096);                   // [4 heads][E 256|F 256]
    unsigned int* lut = (unsigned int*)(smem + 6144);   // 128 B
    char* hts = (char*)smem + 8192;                     // [4 heads][32 d][256 B]

    const int t = threadIdx.x, lane = t & 63, w8 = t >> 6;   // w8 = 0..7
    const int hw = w8 & 3, ihalf = w8 >> 2;
    const int L = blockIdx.x;
    const int b = (L & 7) + 8 * ((L >> 3) & 1);         // batch -> XCD pinning
    const int ibase = (L >> 4) * 32;
    const int i = lane & 15, q = lane >> 4;

    // ---- phase A: in-lane pack (adj is 0/1); wave w8 packs rows w8*4..+3
    {
        const int m = lane & 31, rh = lane >> 5;
        const int r0 = w8 * 4 + rh;
        const int r1 = r0 + 2;
        const int4v* s0 = (const int4v*)(adj + ((size_t)(b * Ndim + ibase + r0)) * Ndim + m * 32);
        const int4v* s1 = (const int4v*)(adj + ((size_t)(b * Ndim + ibase + r1)) * Ndim + m * 32);
        int4v va[8], vb[8];
        #pragma unroll
        for (int u = 0; u < 8; ++u) va[u] = __builtin_nontemporal_load(s0 + u);
        #pragma unroll
        for (int u = 0; u < 8; ++u) vb[u] = __builtin_nontemporal_load(s1 + u);
        unsigned wa = 0, wb_ = 0;
        #pragma unroll
        for (int u = 0; u < 8; ++u) {
            unsigned na  = (unsigned)(va[u][0] | (va[u][1] << 1) | (va[u][2] << 2) | (va[u][3] << 3));
            unsigned nb_ = (unsigned)(vb[u][0] | (vb[u][1] << 1) | (vb[u][2] << 2) | (vb[u][3] << 3));
            wa  |= na  << (4 * u);
            wb_ |= nb_ << (4 * u);
        }
        pkl[r0 * 32 + ((m + r0) & 31)] = wa;   // +row rotation kills bank alias
        pkl[r1 * 32 + ((m + r1) & 31)] = wb_;
    }
    if (t < 16) {   // 2 adj bits -> half2 mask pair
        lut[t * 2]     = ((t & 1) ? 0xFFFFu : 0u) | ((t & 2) ? 0xFFFF0000u : 0u);
        lut[t * 2 + 1] = ((t & 4) ? 0xFFFFu : 0u) | ((t & 8) ? 0xFFFF0000u : 0u);
    }
    // Ei/Fi broadcast constants (node ibase + ihalf*16 + i, head hw)
    const size_t eidx = (size_t)(b * Hh + hw) * Ndim + ibase + ihalf * 16 + i;
    const unsigned Eu = eiE[eidx], Fu = eiF[eidx];
    const unsigned EE = Eu | (Eu << 16);
    const unsigned FF = Fu | (Fu << 16);
    __syncthreads();   // pk+lut visible; phase-A vmem drained

    const char* ghh = (const char*)(hT + (size_t)(b * HDc + hw * 32) * Ndim);
    const int myrow = ihalf * 16 + i;        // pk row for compute
    const char* hrow0 = hts + (hw * 32 + i) * 256;
    const char* hrow1 = hrow0 + 16 * 256;
    const char* ejw   = ejl + hw * 512;
    const uint2v* lut2 = (const uint2v*)lut;
    // ej DMA mapping (waves 0,1 only): head = w8*2+(lane>>5), E/F = (lane>>4)&1
    const char* esrc;
    {
        int hsel = w8 * 2 + (lane >> 5);
        int tab  = (lane >> 4) & 1;
        const unsigned short* base = tab ? ejF : ejE;
        esrc = (const char*)(base + (size_t)(b * Hh + hsel) * Ndim) + (lane & 15) * 16;
    }
    // hT DMA mapping: 4 instrs/wave, d = ihalf*16 + u*4 + (lane>>4)
    const int ddma = ihalf * 16 + (lane >> 4);

    half8 ONES;
    #pragma unroll
    for (int e = 0; e < 8; ++e) ONES[e] = (_Float16)1.0f;

    float4v C0 = {0.f, 0.f, 0.f, 0.f};
    float4v C1 = {0.f, 0.f, 0.f, 0.f};
    float4v C2 = {0.f, 0.f, 0.f, 0.f};   // den via ones-column MFMA

    for (int ch = 0; ch < 8; ++ch) {
        if (ch) __syncthreads();
        // stage hT chunk: wave covers its (head, d-half): 4 KB
        #pragma unroll
        for (int u = 0; u < 4; ++u) {
            int d = ddma + u * 4;
            int c = (lane & 15) ^ (d & 15);
            gl_lds16(ghh + (size_t)d * 2048 + ch * 256 + c * 16,
                     hts + (hw * 32 + ihalf * 16 + u * 4) * 256);
        }
        if (w8 < 2) gl_lds16(esrc + ch * 256, ejl + w8 * 1024);
        __syncthreads();   // vmcnt(0) drain = DMA completion

        #pragma unroll
        for (int jtl = 0; jtl < 4; ++jtl) {
            const int jt = ch * 4 + jtl;
            const int sb = jtl * 4 + q;
            half8 Bh0 = *(const half8*)(hrow0 + ((sb ^ i) << 4));
            half8 Bh1 = *(const half8*)(hrow1 + ((sb ^ i) << 4));
            int4v Ejp = *(const int4v*)(ejw + (sb << 4));
            int4v Fjp = *(const int4v*)(ejw + 256 + (sb << 4));
            unsigned bits = (pkl[myrow * 32 + ((jt + myrow) & 31)] >> (q * 8)) & 0xffu;
            uint2v m0 = lut2[bits & 15];
            uint2v m1 = lut2[bits >> 4];

            union { unsigned u[4]; half8 v; } A;
            A.u[0] = pmax_mask(EE, FF, (unsigned)Ejp[0], (unsigned)Fjp[0], m0[0]);
            A.u[1] = pmax_mask(EE, FF, (unsigned)Ejp[1], (unsigned)Fjp[1], m0[1]);
            A.u[2] = pmax_mask(EE, FF, (unsigned)Ejp[2], (unsigned)Fjp[2], m1[0]);
            A.u[3] = pmax_mask(EE, FF, (unsigned)Ejp[3], (unsigned)Fjp[3], m1[1]);

            C0 = __builtin_amdgcn_mfma_f32_16x16x32_f16(A.v, Bh0, C0, 0, 0, 0);
            C1 = __builtin_amdgcn_mfma_f32_16x16x32_f16(A.v, Bh1, C1, 0, 0, 0);
            C2 = __builtin_amdgcn_mfma_f32_16x16x32_f16(A.v, ONES, C2, 0, 0, 0);
        }
    }

    // C/D layout: col = lane&15 (feature), row = q*4+reg (node)
    float* outp = out + ((size_t)(b * Ndim + ibase + ihalf * 16)) * HDc + hw * 32 + i;
    #pragma unroll
    for (int reg = 0; reg < 4; ++reg) {
        int row = q * 4 + reg;
        float rd = 1.0f / C2[reg];
        outp[(size_t)row * HDc]      = C0[reg] * rd;
        outp[(size_t)row * HDc + 16] = C1[reg] * rd;
    }
}

extern "C" void kernel_launch(void* const* d_in, const int* in_sizes, int n_in,
                              void* d_out, int out_size, void* d_ws, size_t ws_size,
                              hipStream_t stream) {
    const float* x    = (const float*)d_in[0];
    const int*   adj  = (const int*)d_in[1];
    const float* W    = (const float*)d_in[2];
    const float* bias = (const float*)d_in[3];
    const float* a    = (const float*)d_in[4];
    float* out = (float*)d_out;

    // ws: hT 4MB | eiE/eiF/ejE/ejF 128KB ea | WTh 36K | WTl 36K | bias2
    unsigned short* hT  = (unsigned short*)d_ws;
    unsigned short* eiE = hT  + (size_t)Bdim * HDc * Ndim;
    unsigned short* eiF = eiE + (size_t)Bdim * Hh * Ndim;
    unsigned short* ejE = eiF + (size_t)Bdim * Hh * Ndim;
    unsigned short* ejF = ejE + (size_t)Bdim * Hh * Ndim;
    unsigned short* WTh = ejF + (size_t)Bdim * Hh * Ndim;
    unsigned short* WTl = WTh + 144 * 128;
    float* bias2 = (float*)(WTl + 144 * 128);

    split_w_kernel<<<dim3(17), dim3(256), 0, stream>>>(W, bias, a, WTh, WTl, bias2);
    proj_kernel<<<dim3(256), dim3(256), 0, stream>>>(
        x, WTh, WTl, bias2, hT, eiE, eiF, ejE, ejF);
    gat_kernel<<<dim3(512), dim3(512), 0, stream>>>(
        adj, hT, eiE, eiF, ejE, ejF, out);
}

// Round 11
// 150.862 us; speedup vs baseline: 1.0613x; 1.0613x over previous
//
#include <hip/hip_runtime.h>
#include <hip/hip_bf16.h>

#define Bdim 16
#define Ndim 1024
#define Hh   4
#define HDc  128
#define L2E  1.4426950408889634f

typedef float  float4v  __attribute__((ext_vector_type(4)));
typedef int    int4v    __attribute__((ext_vector_type(4)));
typedef short  short8   __attribute__((ext_vector_type(8)));
typedef unsigned short ushort4v __attribute__((ext_vector_type(4)));
typedef unsigned int   uint2v   __attribute__((ext_vector_type(2)));
typedef _Float16 f16x2 __attribute__((ext_vector_type(2)));
typedef _Float16 half8 __attribute__((ext_vector_type(8)));

__device__ __forceinline__ unsigned short bf16_rne(float f) {
    unsigned u = __float_as_uint(f);
    u = u + 0x7FFFu + ((u >> 16) & 1u);
    return (unsigned short)(u >> 16);
}
__device__ __forceinline__ unsigned short f16u(float f) {
    union { _Float16 h; unsigned short u; } c; c.h = (_Float16)f; return c.u;
}
__device__ __forceinline__ void gl_lds16(const void* g, void* l) {
    __builtin_amdgcn_global_load_lds(
        (const __attribute__((address_space(1))) unsigned int*)g,
        (__attribute__((address_space(3))) unsigned int*)l, 16, 0, 0);
}
// p2 = max(EE*Ej2, FF*Fj2) & mask   (packed fp16, 4 VALU for 2 scores)
__device__ __forceinline__ unsigned pmax_mask(unsigned EE, unsigned FF,
                                              unsigned Ej, unsigned Fj, unsigned m) {
    union { unsigned u; f16x2 h; } a, b, c, d, r;
    a.u = EE; b.u = Ej; c.u = FF; d.u = Fj;
    r.h = __builtin_elementwise_max(a.h * b.h, c.h * d.h);
    return r.u & m;
}

// ---------- pack: adj (64MB) -> pre-rotated bitmask (2MB) -------------------
// One word per thread: 8 contiguous int4 loads, in-lane pack, one store.
// No ballots/barriers -> latency hidden by 32 waves/CU, sinking harmless.
__global__ __launch_bounds__(256) void pack_kernel(
    const int* __restrict__ adj, unsigned int* __restrict__ pk)
{
    const int g = blockIdx.x * 256 + threadIdx.x;   // word index 0..524287
    const int n = g >> 5;                            // global row (b*1024 + i)
    const int c = g & 31;                            // word within row
    const int4v* src = (const int4v*)(adj + (size_t)g * 32);
    int4v v[8];
    #pragma unroll
    for (int u = 0; u < 8; ++u) v[u] = __builtin_nontemporal_load(src + u);
    unsigned wd = 0;
    #pragma unroll
    for (int u = 0; u < 8; ++u) {
        unsigned nib = (unsigned)(v[u][0] | (v[u][1] << 1) | (v[u][2] << 2) | (v[u][3] << 3));
        wd |= nib << (4 * u);
    }
    const int r = n & 31;    // row within gat's 32-row block -> bake LDS rotation
    pk[(size_t)n * 32 + ((c + r) & 31)] = wd;
}

// ---------- split_w: WT hi/lo [144][128] row-major + bias2[144] -------------
__global__ __launch_bounds__(256) void split_w_kernel(
    const float* __restrict__ W, const float* __restrict__ bias,
    const float* __restrict__ a,
    unsigned short* __restrict__ WTh, unsigned short* __restrict__ WTl,
    float* __restrict__ bias2)
{
    const int t = threadIdx.x, blk = blockIdx.x;
    if (blk < 16) {
        int r  = blk * 8 + (t >> 5);
        int k0 = (t & 31) * 4;
        #pragma unroll
        for (int j = 0; j < 4; ++j) {
            float f = W[(size_t)(k0 + j) * HDc + r];
            unsigned short hi = bf16_rne(f);
            WTh[r * 128 + k0 + j] = hi;
            WTl[r * 128 + k0 + j] = bf16_rne(f - __uint_as_float((unsigned)hi << 16));
        }
    } else {
        #pragma unroll
        for (int rep = 0; rep < 2; ++rep) {
            int task = t + rep * 256;
            int row = task >> 2, hh = task & 3;
            float si = 0.f, sj = 0.f;
            #pragma unroll
            for (int d4 = 0; d4 < 8; ++d4) {
                float4v wv = *(const float4v*)(W + (size_t)row * HDc + hh * 32 + d4 * 4);
                float4v av = *(const float4v*)(a + d4 * 4);
                float4v bv = *(const float4v*)(a + 32 + d4 * 4);
                #pragma unroll
                for (int kk = 0; kk < 4; ++kk) {
                    si = fmaf(wv[kk], av[kk], si);
                    sj = fmaf(wv[kk], bv[kk], sj);
                }
            }
            float vi = si * L2E, vj = sj * L2E;
            unsigned short hi = bf16_rne(vi);
            WTh[(128 + hh) * 128 + row] = hi;
            WTl[(128 + hh) * 128 + row] = bf16_rne(vi - __uint_as_float((unsigned)hi << 16));
            unsigned short hj = bf16_rne(vj);
            WTh[(132 + hh) * 128 + row] = hj;
            WTl[(132 + hh) * 128 + row] = bf16_rne(vj - __uint_as_float((unsigned)hj << 16));
        }
        #pragma unroll
        for (int rp = 0; rp < 4; ++rp) {
            int idx = t + rp * 256;
            WTh[136 * 128 + idx] = 0;
            WTl[136 * 128 + idx] = 0;
        }
        if (t < 128) {
            bias2[t] = bias[t];
        } else if (t < 136) {
            int z = t - 128;
            const float* av = (z < 4) ? a : a + 32;
            int hh = z & 3;
            float s = 0.f;
            for (int d = 0; d < 32; ++d) s = fmaf(bias[hh * 32 + d], av[d], s);
            bias2[128 + z] = s * L2E;
        } else if (t < 144) {
            bias2[t] = 0.f;
        }
    }
}

// ---------- proj: h (fp16, transposed) + per-node E/F score tables ----------
__global__ __launch_bounds__(256, 1) void proj_kernel(
    const float* __restrict__ x,
    const unsigned short* __restrict__ WTg_h, const unsigned short* __restrict__ WTg_l,
    const float* __restrict__ bias2,
    unsigned short* __restrict__ hT,
    unsigned short* __restrict__ eiE, unsigned short* __restrict__ eiF,
    unsigned short* __restrict__ ejE, unsigned short* __restrict__ ejF)
{
    __shared__ __align__(16) unsigned char smem[106496];  // xs 32K | WT 72K
    char* xls  = (char*)smem;
    char* wtls = (char*)smem + 32768;

    const int t = threadIdx.x, lane = t & 63, w = t >> 6;
    const int l16 = lane & 15, q = lane >> 4;
    const int nb = blockIdx.x * 64;
    const int b = nb >> 10, nloc = nb & 1023;

    {
        const char* gx = (const char*)(x + (size_t)nb * 128);
        int rh = lane >> 5, m = lane & 31;
        #pragma unroll
        for (int d = 0; d < 8; ++d) {
            int r = w * 16 + d * 2 + rh;
            int mg = m ^ (r & 7);
            gl_lds16(gx + (size_t)r * 512 + mg * 16, xls + (size_t)w * 8192 + d * 1024);
        }
    }
    {
        int rh = lane >> 4, m = lane & 15;
        #pragma unroll
        for (int d = 0; d < 18; ++d) {
            int n = w * 18 + d;
            if (n < 36) {
                int r = n * 4 + rh;
                gl_lds16((const char*)WTg_h + (size_t)r * 256 + (m ^ (r & 15)) * 16,
                         wtls + (size_t)n * 1024);
            } else {
                int r = (n - 36) * 4 + rh;
                gl_lds16((const char*)WTg_l + (size_t)r * 256 + (m ^ (r & 15)) * 16,
                         wtls + (size_t)n * 1024);
            }
        }
    }
    __syncthreads();

    float4v C[9];
    #pragma unroll
    for (int nt = 0; nt < 9; ++nt) C[nt] = (float4v){0.f, 0.f, 0.f, 0.f};

    #pragma unroll
    for (int ks = 0; ks < 4; ++ks) {
        short8 Ah, Al;
        {
            int r = w * 16 + l16;
            int c0 = (ks * 8 + q * 2) ^ (l16 & 7);
            int c1 = (ks * 8 + q * 2 + 1) ^ (l16 & 7);
            float4v x0 = *(const float4v*)(xls + (size_t)r * 512 + c0 * 16);
            float4v x1 = *(const float4v*)(xls + (size_t)r * 512 + c1 * 16);
            #pragma unroll
            for (int e = 0; e < 8; ++e) {
                float f = (e < 4) ? x0[e] : x1[e - 4];
                unsigned short hi = bf16_rne(f);
                Ah[e] = (short)hi;
                Al[e] = (short)bf16_rne(f - __uint_as_float((unsigned)hi << 16));
            }
        }
        #pragma unroll
        for (int nt = 0; nt < 9; ++nt) {
            const char* wb = wtls + (size_t)(nt * 16 + l16) * 256 + ((ks * 4 + q) ^ l16) * 16;
            short8 Bh = *(const short8*)wb;
            short8 Bl = *(const short8*)(wb + 36864);
            C[nt] = __builtin_amdgcn_mfma_f32_16x16x32_bf16(Ah, Bh, C[nt], 0, 0, 0);
            C[nt] = __builtin_amdgcn_mfma_f32_16x16x32_bf16(Ah, Bl, C[nt], 0, 0, 0);
            C[nt] = __builtin_amdgcn_mfma_f32_16x16x32_bf16(Al, Bh, C[nt], 0, 0, 0);
        }
    }

    {
        int node = nloc + w * 16 + q * 4;
        #pragma unroll
        for (int nt = 0; nt < 8; ++nt) {
            int col = nt * 16 + l16;
            float bv = bias2[col];
            ushort4v h4;
            #pragma unroll
            for (int r = 0; r < 4; ++r) h4[r] = f16u(C[nt][r] + bv);
            *(ushort4v*)(hT + (size_t)(b * HDc + col) * Ndim + node) = h4;
        }
        float bv = bias2[128 + l16];
        if (l16 < 8) {
            int hh = l16 & 3;
            ushort4v Ev, Fv;
            #pragma unroll
            for (int r = 0; r < 4; ++r) {
                float v = C[8][r] + bv;                 // already * log2e
                Ev[r] = f16u(__builtin_amdgcn_exp2f(v));
                Fv[r] = f16u(__builtin_amdgcn_exp2f(0.2f * v));
            }
            size_t off = (size_t)(b * Hh + hh) * Ndim + node;
            if (l16 < 4) { *(ushort4v*)(eiE + off) = Ev; *(ushort4v*)(eiF + off) = Fv; }
            else         { *(ushort4v*)(ejE + off) = Ev; *(ushort4v*)(ejF + off) = Fv; }
        }
    }
}

// ---------- gat: 32 i-rows x 4 heads, 512 threads; NO adj phase (pk via DMA) -
__global__ __launch_bounds__(512, 4) void gat_kernel(
    const unsigned int* __restrict__ pk, const unsigned short* __restrict__ hT,
    const unsigned short* __restrict__ eiE, const unsigned short* __restrict__ eiF,
    const unsigned short* __restrict__ ejE, const unsigned short* __restrict__ ejF,
    float* __restrict__ out)
{
    __shared__ __align__(16) unsigned char smem[40960]; // pk 4K|ej 2K|lut|hT 32K
    unsigned int* pkl = (unsigned int*)smem;            // [32 rows][32 words, pre-rotated]
    char* ejl = (char*)(smem + 4096);                   // [4 heads][E 256|F 256]
    unsigned int* lut = (unsigned int*)(smem + 6144);   // 128 B
    char* hts = (char*)smem + 8192;                     // [4 heads][32 d][256 B]

    const int t = threadIdx.x, lane = t & 63, w8 = t >> 6;   // w8 = 0..7
    const int hw = w8 & 3, ihalf = w8 >> 2;
    const int L = blockIdx.x;
    const int b = (L & 7) + 8 * ((L >> 3) & 1);         // batch -> XCD pinning
    const int ibase = (L >> 4) * 32;
    const int i = lane & 15, q = lane >> 4;

    // ---- pk DMA: 4 KB, waves 0-3 stage 1 KB each (pre-rotated upstream)
    if (w8 < 4)
        gl_lds16((const char*)(pk + (size_t)(b * Ndim + ibase) * 32) + w8 * 1024 + lane * 16,
                 (char*)pkl + w8 * 1024);
    if (t < 16) {   // 2 adj bits -> half2 mask pair
        lut[t * 2]     = ((t & 1) ? 0xFFFFu : 0u) | ((t & 2) ? 0xFFFF0000u : 0u);
        lut[t * 2 + 1] = ((t & 4) ? 0xFFFFu : 0u) | ((t & 8) ? 0xFFFF0000u : 0u);
    }
    // Ei/Fi broadcast constants (node ibase + ihalf*16 + i, head hw)
    const size_t eidx = (size_t)(b * Hh + hw) * Ndim + ibase + ihalf * 16 + i;
    const unsigned Eu = eiE[eidx], Fu = eiF[eidx];
    const unsigned EE = Eu | (Eu << 16);
    const unsigned FF = Fu | (Fu << 16);
    __syncthreads();   // pk+lut visible; all vmem drained

    const char* ghh = (const char*)(hT + (size_t)(b * HDc + hw * 32) * Ndim);
    const int myrow = ihalf * 16 + i;        // pk row for compute
    const char* hrow0 = hts + (hw * 32 + i) * 256;
    const char* hrow1 = hrow0 + 16 * 256;
    const char* ejw   = ejl + hw * 512;
    const uint2v* lut2 = (const uint2v*)lut;
    // ej DMA mapping (waves 0,1 only): head = w8*2+(lane>>5), E/F = (lane>>4)&1
    const char* esrc;
    {
        int hsel = w8 * 2 + (lane >> 5);
        int tab  = (lane >> 4) & 1;
        const unsigned short* base = tab ? ejF : ejE;
        esrc = (const char*)(base + (size_t)(b * Hh + hsel) * Ndim) + (lane & 15) * 16;
    }
    // hT DMA mapping: 4 instrs/wave, d = ihalf*16 + u*4 + (lane>>4)
    const int ddma = ihalf * 16 + (lane >> 4);

    half8 ONES;
    #pragma unroll
    for (int e = 0; e < 8; ++e) ONES[e] = (_Float16)1.0f;

    float4v C0 = {0.f, 0.f, 0.f, 0.f};
    float4v C1 = {0.f, 0.f, 0.f, 0.f};
    float4v C2 = {0.f, 0.f, 0.f, 0.f};   // den via ones-column MFMA

    for (int ch = 0; ch < 8; ++ch) {
        if (ch) __syncthreads();
        // stage hT chunk: wave covers its (head, d-half): 4 KB
        #pragma unroll
        for (int u = 0; u < 4; ++u) {
            int d = ddma + u * 4;
            int c = (lane & 15) ^ (d & 15);
            gl_lds16(ghh + (size_t)d * 2048 + ch * 256 + c * 16,
                     hts + (hw * 32 + ihalf * 16 + u * 4) * 256);
        }
        if (w8 < 2) gl_lds16(esrc + ch * 256, ejl + w8 * 1024);
        __syncthreads();   // vmcnt(0) drain = DMA completion

        #pragma unroll
        for (int jtl = 0; jtl < 4; ++jtl) {
            const int jt = ch * 4 + jtl;
            const int sb = jtl * 4 + q;
            half8 Bh0 = *(const half8*)(hrow0 + ((sb ^ i) << 4));
            half8 Bh1 = *(const half8*)(hrow1 + ((sb ^ i) << 4));
            int4v Ejp = *(const int4v*)(ejw + (sb << 4));
            int4v Fjp = *(const int4v*)(ejw + 256 + (sb << 4));
            unsigned bits = (pkl[myrow * 32 + ((jt + myrow) & 31)] >> (q * 8)) & 0xffu;
            uint2v m0 = lut2[bits & 15];
            uint2v m1 = lut2[bits >> 4];

            union { unsigned u[4]; half8 v; } A;
            A.u[0] = pmax_mask(EE, FF, (unsigned)Ejp[0], (unsigned)Fjp[0], m0[0]);
            A.u[1] = pmax_mask(EE, FF, (unsigned)Ejp[1], (unsigned)Fjp[1], m0[1]);
            A.u[2] = pmax_mask(EE, FF, (unsigned)Ejp[2], (unsigned)Fjp[2], m1[0]);
            A.u[3] = pmax_mask(EE, FF, (unsigned)Ejp[3], (unsigned)Fjp[3], m1[1]);

            C0 = __builtin_amdgcn_mfma_f32_16x16x32_f16(A.v, Bh0, C0, 0, 0, 0);
            C1 = __builtin_amdgcn_mfma_f32_16x16x32_f16(A.v, Bh1, C1, 0, 0, 0);
            C2 = __builtin_amdgcn_mfma_f32_16x16x32_f16(A.v, ONES, C2, 0, 0, 0);
        }
    }

    // C/D layout: col = lane&15 (feature), row = q*4+reg (node)
    float* outp = out + ((size_t)(b * Ndim + ibase + ihalf * 16)) * HDc + hw * 32 + i;
    #pragma unroll
    for (int reg = 0; reg < 4; ++reg) {
        int row = q * 4 + reg;
        float rd = 1.0f / C2[reg];
        outp[(size_t)row * HDc]      = C0[reg] * rd;
        outp[(size_t)row * HDc + 16] = C1[reg] * rd;
    }
}

extern "C" void kernel_launch(void* const* d_in, const int* in_sizes, int n_in,
                              void* d_out, int out_size, void* d_ws, size_t ws_size,
                              hipStream_t stream) {
    const float* x    = (const float*)d_in[0];
    const int*   adj  = (const int*)d_in[1];
    const float* W    = (const float*)d_in[2];
    const float* bias = (const float*)d_in[3];
    const float* a    = (const float*)d_in[4];
    float* out = (float*)d_out;

    // ws: pk 2MB | hT 4MB | eiE/eiF/ejE/ejF 128KB ea | WTh/WTl 36K ea | bias2
    unsigned int*   pk  = (unsigned int*)d_ws;
    unsigned short* hT  = (unsigned short*)((char*)d_ws + 2 * 1024 * 1024);
    unsigned short* eiE = hT  + (size_t)Bdim * HDc * Ndim;
    unsigned short* eiF = eiE + (size_t)Bdim * Hh * Ndim;
    unsigned short* ejE = eiF + (size_t)Bdim * Hh * Ndim;
    unsigned short* ejF = ejE + (size_t)Bdim * Hh * Ndim;
    unsigned short* WTh = ejF + (size_t)Bdim * Hh * Ndim;
    unsigned short* WTl = WTh + 144 * 128;
    float* bias2 = (float*)(WTl + 144 * 128);

    split_w_kernel<<<dim3(17), dim3(256), 0, stream>>>(W, bias, a, WTh, WTl, bias2);
    pack_kernel<<<dim3(2048), dim3(256), 0, stream>>>(adj, pk);
    proj_kernel<<<dim3(256), dim3(256), 0, stream>>>(
        x, WTh, WTl, bias2, hT, eiE, eiF, ejE, ejF);
    gat_kernel<<<dim3(512), dim3(512), 0, stream>>>(
        pk, hT, eiE, eiF, ejE, ejF, out);
}